// Round 1
// baseline (229.610 us; speedup 1.0000x reference)
//
#include <hip/hip_runtime.h>

// OIM unsupervised loss, MI355X/gfx950.
// Strategy: error-compensated bf16 MFMA GEMM (hi/lo split, augmented K=768)
//   A' = [hi(x) | hi(x) | lo(x)]  (4096 x 768)
//   B' = [hi(b) | lo(b) | hi(b)]  (10240 x 768; rows 0..4999 lut_instance,
//         5120..10119 reid_lut, pads zeroed)
//   dot(A',B') = hi*hi + hi*lo + lo*hi  (~f32 accuracy)
// Main kernel: 128x128 tiles, 4 waves, 4x4 fragments of mfma_f32_16x16x32_bf16,
// fragment-linear operand layout in ws so global_load_lds stages LDS directly.
// Per-row online logsumexp partials -> combine kernel -> deterministic finalize.

#define BT 4096
#define NPID 5000
#define FDIM 256
#define KAUG 768
#define NCHUNK 24        // KAUG / 32
#define BPROWS 10240
#define SIDE 5120
#define NEGF -1e30f

typedef __attribute__((ext_vector_type(8))) short short8;
typedef __attribute__((ext_vector_type(4))) float f32x4;

__device__ __forceinline__ unsigned short f2bf_rne(float f) {
  unsigned int u = __float_as_uint(f);
  u += 0x7fffu + ((u >> 16) & 1u);
  return (unsigned short)(u >> 16);
}
__device__ __forceinline__ float bf2f(unsigned short h) {
  return __uint_as_float(((unsigned int)h) << 16);
}

// 16B-unit index of (row, oct) in fragment-linear layout.
// oct in [0,96): 8-element group along augmented K.
// lane order inside a 1KB frag-block: lane = (row&15) + 16*ko, 8 bf16 each.
__device__ __forceinline__ size_t frag_unit(int row, int oct) {
  int c  = oct >> 2;   // 32-wide k-chunk
  int ko = oct & 3;    // 8-wide oct within chunk
  return ((size_t)(row >> 4) * NCHUNK + c) * 64 + (row & 15) + (ko << 4);
}

__global__ __launch_bounds__(256) void convert_A(const float* __restrict__ x,
                                                 unsigned short* __restrict__ outp) {
  int idx = blockIdx.x * 256 + threadIdx.x;
  if (idx >= BT * 96) return;
  int row = idx / 96, oct = idx % 96;
  int seg = oct >> 5;          // 0,1: hi   2: lo
  int so  = oct & 31;
  const float4* s4 = (const float4*)(x + (size_t)row * FDIM + so * 8);
  float4 f0 = s4[0], f1 = s4[1];
  float fv[8] = {f0.x, f0.y, f0.z, f0.w, f1.x, f1.y, f1.z, f1.w};
  short8 ov;
#pragma unroll
  for (int j = 0; j < 8; ++j) {
    unsigned short hi = f2bf_rne(fv[j]);
    if (seg == 2) hi = f2bf_rne(fv[j] - bf2f(hi));
    ov[j] = (short)hi;
  }
  *(short8*)(outp + frag_unit(row, oct) * 8) = ov;
}

__global__ __launch_bounds__(256) void convert_B(const float* __restrict__ lut,
                                                 const float* __restrict__ reid,
                                                 unsigned short* __restrict__ outp) {
  int idx = blockIdx.x * 256 + threadIdx.x;
  if (idx >= BPROWS * 96) return;
  int row = idx / 96, oct = idx % 96;
  int seg = oct >> 5;          // 0: hi  1: lo  2: hi
  int so  = oct & 31;
  const float* src = nullptr;
  if (row < NPID) src = lut + (size_t)row * FDIM + so * 8;
  else if (row >= SIDE && row < SIDE + NPID) src = reid + (size_t)(row - SIDE) * FDIM + so * 8;
  short8 ov;
  if (src) {
    const float4* s4 = (const float4*)src;
    float4 f0 = s4[0], f1 = s4[1];
    float fv[8] = {f0.x, f0.y, f0.z, f0.w, f1.x, f1.y, f1.z, f1.w};
#pragma unroll
    for (int j = 0; j < 8; ++j) {
      unsigned short hi = f2bf_rne(fv[j]);
      if (seg == 1) hi = f2bf_rne(fv[j] - bf2f(hi));
      ov[j] = (short)hi;
    }
  } else {
#pragma unroll
    for (int j = 0; j < 8; ++j) ov[j] = 0;
  }
  *(short8*)(outp + frag_unit(row, oct) * 8) = ov;
}

// one wave per row: meta flags + feature-consistency SSD
__global__ __launch_bounds__(256) void meta_fc(const float* __restrict__ inputs,
                                               const int* __restrict__ roi,
                                               const float* __restrict__ lut,
                                               const int* __restrict__ rlab,
                                               int* __restrict__ g, int* __restrict__ lr,
                                               float* __restrict__ w2f, float* __restrict__ v1f,
                                               float* __restrict__ fc) {
  int gt = blockIdx.x * 256 + threadIdx.x;
  int row = gt >> 6, lane = gt & 63;
  if (row >= BT) return;
  int t = roi[row] - 1;
  bool valid = t >= 0;
  int label = t > 0 ? t : 0;
  int gg = rlab[label];
  const float4* xv = (const float4*)(inputs + (size_t)row * FDIM);
  const float4* lv = (const float4*)(lut + (size_t)label * FDIM);
  float4 a = xv[lane], b = lv[lane];
  float dx = b.x - a.x, dy = b.y - a.y, dz = b.z - a.z, dw = b.w - a.w;
  float s = dx * dx + dy * dy + dz * dz + dw * dw;
#pragma unroll
  for (int d = 1; d < 64; d <<= 1) s += __shfl_xor(s, d, 64);
  if (lane == 0) {
    g[row]   = gg;
    lr[row]  = gg > 0 ? gg : 0;
    w2f[row] = (valid && gg >= 0) ? 1.0f : 0.0f;
    v1f[row] = valid ? 1.0f : 0.0f;
    fc[row]  = valid ? s : 0.0f;
  }
}

__global__ __launch_bounds__(256) void gemm_main(const unsigned short* __restrict__ Ap,
                                                 const unsigned short* __restrict__ Bp,
                                                 const int* __restrict__ rlab,
                                                 const int* __restrict__ g,
                                                 const int* __restrict__ lr,
                                                 float2* __restrict__ partials,
                                                 float* __restrict__ posbuf,
                                                 int* __restrict__ poscnt,
                                                 float* __restrict__ target) {
  __shared__ unsigned short lds[16384] __attribute__((aligned(16)));  // 32 KB: A 16K + B 16K
  const int cb = blockIdx.x;   // 0..79  (0..39 inst, 40..79 reid); B' row base = cb*128
  const int rb = blockIdx.y;   // 0..31
  const int tid = threadIdx.x;
  const int lane = tid & 63;
  const int w = tid >> 6;
  const int wr = w >> 1, wc = w & 1;

  f32x4 acc[4][4];
#pragma unroll
  for (int i = 0; i < 4; ++i)
#pragma unroll
    for (int j = 0; j < 4; ++j) acc[i][j] = (f32x4){0.f, 0.f, 0.f, 0.f};

  for (int s = 0; s < 12; ++s) {           // K-steps of 64 (2 mfma chunks)
    const int c0 = s * 2;
    __syncthreads();
#pragma unroll
    for (int q = 0; q < 8; ++q) {          // 32 frag-blocks of 1KB, 8 per wave
      const int f = w * 8 + q;
      const bool isA = f < 16;
      const int fl = isA ? f : f - 16;
      const int cc = fl >> 3;
      const int grp = fl & 7;
      const int gidx = isA ? (rb * 8 + grp) : (cb * 8 + grp);
      const unsigned short* src = (isA ? Ap : Bp)
          + (((size_t)gidx * NCHUNK + (c0 + cc)) << 6) * 8 + lane * 8;
      unsigned short* dst = &lds[f * 512];
      __builtin_amdgcn_global_load_lds((const __attribute__((address_space(1))) unsigned int*)src,
                                       (__attribute__((address_space(3))) unsigned int*)dst,
                                       16, 0, 0);
    }
    __syncthreads();
#pragma unroll
    for (int cc = 0; cc < 2; ++cc) {
      short8 af[4], bfr[4];
#pragma unroll
      for (int mr = 0; mr < 4; ++mr)
        af[mr] = *(const short8*)&lds[(cc * 8 + (wr * 4 + mr)) * 512 + lane * 8];
#pragma unroll
      for (int nr = 0; nr < 4; ++nr)
        bfr[nr] = *(const short8*)&lds[8192 + (cc * 8 + (wc * 4 + nr)) * 512 + lane * 8];
#pragma unroll
      for (int mr = 0; mr < 4; ++mr)
#pragma unroll
        for (int nr = 0; nr < 4; ++nr)
          acc[mr][nr] = __builtin_amdgcn_mfma_f32_16x16x32_bf16(af[mr], bfr[nr], acc[mr][nr], 0, 0, 0);
    }
  }

  // ---- epilogue: per-row online (max, sumexp) over this block's 64-col slices ----
  const bool inst = cb < 40;
  const int cbl = inst ? cb : cb - 40;
  int colv[4], rl4[4];
#pragma unroll
  for (int nr = 0; nr < 4; ++nr) {
    colv[nr] = cbl * 128 + wc * 64 + nr * 16 + (lane & 15);   // side-local col
    rl4[nr] = (inst && colv[nr] < NPID) ? rlab[colv[nr]] : (int)0x80000000;
  }
  const int rowbase = rb * 128 + wr * 64 + ((lane >> 4) << 2);

#pragma unroll
  for (int mr = 0; mr < 4; ++mr) {
#pragma unroll
    for (int reg = 0; reg < 4; ++reg) {
      const int row = rowbase + mr * 16 + reg;
      float m = NEGF, ss = 0.f;
      const int grow = inst ? g[row] : 0;
      const int lrow = inst ? 0 : lr[row];
#pragma unroll
      for (int nr = 0; nr < 4; ++nr) {
        float x = acc[mr][nr][reg] * 30.0f;
        const bool cv = colv[nr] < NPID;
        bool incl = cv;
        if (inst) {
          if (cv && rl4[nr] == grow) {          // positive: stash, exclude from lse_neg
            int idx = atomicAdd(&poscnt[row], 1);
            if (idx < 16) posbuf[row * 16 + idx] = x;
            incl = false;
          }
        } else {
          if (cv && colv[nr] == lrow) target[row] = x;  // CE target (stays in lse)
        }
        if (incl) {
          if (x > m) { ss = ss * __expf(m - x) + 1.0f; m = x; }
          else ss += __expf(x - m);
        }
      }
#pragma unroll
      for (int d = 1; d < 16; d <<= 1) {        // merge the 16 lanes sharing this row
        float mo = __shfl_xor(m, d, 64);
        float so = __shfl_xor(ss, d, 64);
        if (mo > m) { ss = ss * __expf(m - mo) + so; m = mo; }
        else ss += so * __expf(mo - m);
      }
      if ((lane & 15) == 0) {
        const int chunk = (inst ? 0 : 80) + cbl * 2 + wc;
        partials[(size_t)row * 160 + chunk] = make_float2(m, ss);
      }
    }
  }
}

__global__ __launch_bounds__(256) void combine(const float2* __restrict__ partials,
                                               const float* __restrict__ posbuf,
                                               const int* __restrict__ poscnt,
                                               const float* __restrict__ target,
                                               const float* __restrict__ w2f,
                                               float* __restrict__ Lrow,
                                               float* __restrict__ Crow) {
  int row = blockIdx.x * 256 + threadIdx.x;
  if (row >= BT) return;
  const float2* p = partials + (size_t)row * 160;
  float M = NEGF, S = 0.f;
  for (int i = 0; i < 80; ++i) {
    float2 q = p[i];
    if (q.x > M) { S = S * __expf(M - q.x) + q.y; M = q.x; }
    else S += q.y * __expf(q.x - M);
  }
  float lse_neg = M + __logf(S);
  int cnt = poscnt[row];
  int cc = cnt < 16 ? cnt : 16;
  float sum = 0.f;
  for (int j = 0; j < cc; ++j) {
    float d = lse_neg - posbuf[row * 16 + j];
    sum += (d > 80.f) ? d : log1pf(__expf(d));
  }
  float w2 = w2f[row];
  Lrow[row] = w2 * (sum / fmaxf((float)cnt, 1.0f));
  float M2 = NEGF, S2 = 0.f;
  for (int i = 80; i < 160; ++i) {
    float2 q = p[i];
    if (q.x > M2) { S2 = S2 * __expf(M2 - q.x) + q.y; M2 = q.x; }
    else S2 += q.y * __expf(q.x - M2);
  }
  float ce = (M2 + __logf(S2)) - target[row];
  Crow[row] = w2 * ce;
}

__global__ __launch_bounds__(256) void finalize(const float* __restrict__ fc,
                                                const float* __restrict__ v1f,
                                                const float* __restrict__ w2f,
                                                const float* __restrict__ Lrow,
                                                const float* __restrict__ Crow,
                                                float* __restrict__ out) {
  int t = threadIdx.x;
  float s0 = 0, s1 = 0, s2 = 0, s3 = 0, s4 = 0;
  for (int r = t; r < BT; r += 256) {
    s0 += fc[r]; s1 += v1f[r]; s2 += w2f[r]; s3 += Lrow[r]; s4 += Crow[r];
  }
#pragma unroll
  for (int d = 1; d < 64; d <<= 1) {
    s0 += __shfl_xor(s0, d, 64);
    s1 += __shfl_xor(s1, d, 64);
    s2 += __shfl_xor(s2, d, 64);
    s3 += __shfl_xor(s3, d, 64);
    s4 += __shfl_xor(s4, d, 64);
  }
  __shared__ float red[4][5];
  int lane = t & 63, wv = t >> 6;
  if (lane == 0) { red[wv][0] = s0; red[wv][1] = s1; red[wv][2] = s2; red[wv][3] = s3; red[wv][4] = s4; }
  __syncthreads();
  if (t == 0) {
    float a0 = 0, a1 = 0, a2 = 0, a3 = 0, a4 = 0;
    for (int i = 0; i < 4; ++i) { a0 += red[i][0]; a1 += red[i][1]; a2 += red[i][2]; a3 += red[i][3]; a4 += red[i][4]; }
    float n1 = fmaxf(a1, 1.0f);
    float n2 = fmaxf(a2, 1.0f);
    out[0] = a0 / (n1 * (float)FDIM) + a4 / n2 + a3 / n2;
  }
}

extern "C" void kernel_launch(void* const* d_in, const int* in_sizes, int n_in,
                              void* d_out, int out_size, void* d_ws, size_t ws_size,
                              hipStream_t stream) {
  const float* inputs = (const float*)d_in[0];
  const int*   roi    = (const int*)d_in[1];
  const float* lut    = (const float*)d_in[2];
  const float* reid   = (const float*)d_in[3];
  const int*   rlab   = (const int*)d_in[4];
  float* out = (float*)d_out;

  char* w = (char*)d_ws;
  unsigned short* Ap = (unsigned short*)(w);                 // 6,291,456 B
  unsigned short* Bp = (unsigned short*)(w + 6291456);       // 15,728,640 B
  float2* partials   = (float2*)(w + 22020096);              // 5,242,880 B
  float*  posbuf     = (float*)(w + 27262976);               // 262,144 B
  int*    poscnt     = (int*)(w + 27525120);                 // 16,384 B
  float*  target     = (float*)(w + 27541504);
  int*    g          = (int*)(w + 27557888);
  int*    lr         = (int*)(w + 27574272);
  float*  w2f        = (float*)(w + 27590656);
  float*  v1f        = (float*)(w + 27607040);
  float*  fc         = (float*)(w + 27623424);
  float*  Lrow       = (float*)(w + 27639808);
  float*  Crow       = (float*)(w + 27656192);               // ends 27,672,576

  hipMemsetAsync(poscnt, 0, BT * sizeof(int), stream);
  convert_A<<<(BT * 96 + 255) / 256, 256, 0, stream>>>(inputs, Ap);
  convert_B<<<(BPROWS * 96 + 255) / 256, 256, 0, stream>>>(lut, reid, Bp);
  meta_fc<<<(BT * 64) / 256, 256, 0, stream>>>(inputs, roi, lut, rlab, g, lr, w2f, v1f, fc);
  gemm_main<<<dim3(80, 32), 256, 0, stream>>>(Ap, Bp, rlab, g, lr, partials, posbuf, poscnt, target);
  combine<<<BT / 256, 256, 0, stream>>>(partials, posbuf, poscnt, target, w2f, Lrow, Crow);
  finalize<<<1, 256, 0, stream>>>(fc, v1f, w2f, Lrow, Crow, out);
}

// Round 2
// 198.068 us; speedup vs baseline: 1.1593x; 1.1593x over previous
//
#include <hip/hip_runtime.h>

// OIM unsupervised loss, MI355X/gfx950 — round 2.
// hi/lo-compensated bf16 GEMM (augmented K=768) with mfma_f32_32x32x16_bf16,
// 256x128 block tile, 4 waves @128x64, BK=32, 2-phase double-buffered LDS,
// base-2 online-softmax epilogue via LDS transpose (XOR swizzle, stride 272B).

#define BT 4096
#define NPID 5000
#define FDIM 256
#define KAUG 768
#define NCH16 48         // KAUG/16
#define BPROWS 10240
#define SIDE 5120
#define NEGF -1e30f
#define SCALE2 43.2808512266689f   // 30*log2(e)
#define LN2 0.6931471805599453f
#define PADMARK ((int)0x80000000)

typedef __attribute__((ext_vector_type(8))) short short8;
typedef __attribute__((ext_vector_type(4))) float f32x4;
typedef __attribute__((ext_vector_type(16))) float f32x16;

__device__ __forceinline__ unsigned short f2bf_rne(float f) {
  unsigned int u = __float_as_uint(f);
  u += 0x7fffu + ((u >> 16) & 1u);
  return (unsigned short)(u >> 16);
}
__device__ __forceinline__ float bf2f(unsigned short h) {
  return __uint_as_float(((unsigned int)h) << 16);
}

// 16B-unit index of (row, oct) in 32x32x16 fragment-linear layout.
// frag-block = 32 rows x 16 k = 1KB; lane = (row&31) + 32*(k>>3).
__device__ __forceinline__ size_t frag_unit(int row, int oct) {
  int chunk = oct >> 1;    // 16-wide k-chunk
  int half  = oct & 1;     // 8-wide octet within chunk
  return ((size_t)(row >> 5) * NCH16 + chunk) * 64 + (row & 31) + (half << 5);
}

__global__ __launch_bounds__(256) void convert_A(const float* __restrict__ x,
                                                 unsigned short* __restrict__ outp) {
  int idx = blockIdx.x * 256 + threadIdx.x;
  if (idx >= BT * 96) return;
  int row = idx / 96, oct = idx % 96;
  int seg = oct >> 5;          // 0,1: hi   2: lo
  int so  = oct & 31;
  const float4* s4 = (const float4*)(x + (size_t)row * FDIM + so * 8);
  float4 f0 = s4[0], f1 = s4[1];
  float fv[8] = {f0.x, f0.y, f0.z, f0.w, f1.x, f1.y, f1.z, f1.w};
  short8 ov;
#pragma unroll
  for (int j = 0; j < 8; ++j) {
    unsigned short hi = f2bf_rne(fv[j]);
    if (seg == 2) hi = f2bf_rne(fv[j] - bf2f(hi));
    ov[j] = (short)hi;
  }
  *(short8*)(outp + frag_unit(row, oct) * 8) = ov;
}

__global__ __launch_bounds__(256) void convert_B(const float* __restrict__ lut,
                                                 const float* __restrict__ reid,
                                                 unsigned short* __restrict__ outp) {
  int idx = blockIdx.x * 256 + threadIdx.x;
  if (idx >= BPROWS * 96) return;
  int row = idx / 96, oct = idx % 96;
  int seg = oct >> 5;          // 0: hi  1: lo  2: hi
  int so  = oct & 31;
  const float* src = nullptr;
  if (row < NPID) src = lut + (size_t)row * FDIM + so * 8;
  else if (row >= SIDE && row < SIDE + NPID) src = reid + (size_t)(row - SIDE) * FDIM + so * 8;
  short8 ov;
  if (src) {
    const float4* s4 = (const float4*)src;
    float4 f0 = s4[0], f1 = s4[1];
    float fv[8] = {f0.x, f0.y, f0.z, f0.w, f1.x, f1.y, f1.z, f1.w};
#pragma unroll
    for (int j = 0; j < 8; ++j) {
      unsigned short hi = f2bf_rne(fv[j]);
      if (seg == 1) hi = f2bf_rne(fv[j] - bf2f(hi));
      ov[j] = (short)hi;
    }
  } else {
#pragma unroll
    for (int j = 0; j < 8; ++j) ov[j] = 0;
  }
  *(short8*)(outp + frag_unit(row, oct) * 8) = ov;
}

__global__ __launch_bounds__(256) void meta_fc(const float* __restrict__ inputs,
                                               const int* __restrict__ roi,
                                               const float* __restrict__ lut,
                                               const int* __restrict__ rlab,
                                               int* __restrict__ g, int* __restrict__ lr,
                                               float* __restrict__ w2f, float* __restrict__ v1f,
                                               float* __restrict__ fc) {
  int gt = blockIdx.x * 256 + threadIdx.x;
  int row = gt >> 6, lane = gt & 63;
  if (row >= BT) return;
  int t = roi[row] - 1;
  bool valid = t >= 0;
  int label = t > 0 ? t : 0;
  int gg = rlab[label];
  const float4* xv = (const float4*)(inputs + (size_t)row * FDIM);
  const float4* lv = (const float4*)(lut + (size_t)label * FDIM);
  float4 a = xv[lane], b = lv[lane];
  float dx = b.x - a.x, dy = b.y - a.y, dz = b.z - a.z, dw = b.w - a.w;
  float s = dx * dx + dy * dy + dz * dz + dw * dw;
#pragma unroll
  for (int d = 1; d < 64; d <<= 1) s += __shfl_xor(s, d, 64);
  if (lane == 0) {
    g[row]   = gg;
    lr[row]  = gg > 0 ? gg : 0;
    w2f[row] = (valid && gg >= 0) ? 1.0f : 0.0f;
    v1f[row] = valid ? 1.0f : 0.0f;
    fc[row]  = valid ? s : 0.0f;
  }
}

__global__ __launch_bounds__(256) void gemm_main(const unsigned short* __restrict__ Ap,
                                                 const unsigned short* __restrict__ Bp,
                                                 const int* __restrict__ rlab,
                                                 const int* __restrict__ g,
                                                 const int* __restrict__ lr,
                                                 float2* __restrict__ partials,
                                                 float* __restrict__ posbuf,
                                                 int* __restrict__ poscnt,
                                                 float* __restrict__ target) {
  extern __shared__ __align__(16) char smem[];
  // bijective XCD swizzle: 1280 blocks, 160 per XCD -> each XCD owns 2 row-panels
  const int bid = blockIdx.x;
  const int wg = ((bid & 7) * 160) + (bid >> 3);
  const int cb = wg % 80;        // col tile (0..39 inst, 40..79 reid)
  const int rb = wg / 80;        // row tile
  const int tid = threadIdx.x;
  const int l = tid & 63;
  const int w = tid >> 6;
  const int wr = w >> 1, wc = w & 1;

  f32x16 acc[4][2];
#pragma unroll
  for (int i = 0; i < 4; ++i)
#pragma unroll
    for (int j = 0; j < 2; ++j)
#pragma unroll
      for (int r = 0; r < 16; ++r) acc[i][j][r] = 0.f;

  auto stage = [&](int s, int buf) {
    const int base = buf * 24576;
#pragma unroll
    for (int q = 0; q < 6; ++q) {
      const int f = w * 6 + q;               // 24 frag-blocks: 16 A + 8 B
      const unsigned short* src;
      int dstoff;
      if (f < 16) {
        int ch = f >> 3, rg = f & 7;
        src = Ap + (((size_t)(rb * 8 + rg) * NCH16 + s * 2 + ch) << 9);
        dstoff = base + (ch * 8 + rg) * 1024;
      } else {
        int f2 = f - 16, ch = f2 >> 2, cg = f2 & 3;
        src = Bp + (((size_t)(cb * 4 + cg) * NCH16 + s * 2 + ch) << 9);
        dstoff = base + 16384 + (ch * 4 + cg) * 1024;
      }
      __builtin_amdgcn_global_load_lds(
          (const __attribute__((address_space(1))) unsigned int*)(src + l * 8),
          (__attribute__((address_space(3))) unsigned int*)(smem + dstoff), 16, 0, 0);
    }
  };

  stage(0, 0);
  int cur = 0;
  for (int s = 0; s < 24; ++s) {             // BK=32 steps
    __syncthreads();                         // drains vmcnt -> buf[cur] ready
    if (s < 23) stage(s + 1, cur ^ 1);       // prefetch overlaps compute below
    const int base = cur * 24576;
#pragma unroll
    for (int cc = 0; cc < 2; ++cc) {
      short8 af[4], bf[2];
#pragma unroll
      for (int mr = 0; mr < 4; ++mr)
        af[mr] = *(const short8*)(smem + base + (cc * 8 + wr * 4 + mr) * 1024 + l * 16);
#pragma unroll
      for (int nr = 0; nr < 2; ++nr)
        bf[nr] = *(const short8*)(smem + base + 16384 + (cc * 4 + wc * 2 + nr) * 1024 + l * 16);
#pragma unroll
      for (int mr = 0; mr < 4; ++mr)
#pragma unroll
        for (int nr = 0; nr < 2; ++nr)
          acc[mr][nr] = __builtin_amdgcn_mfma_f32_32x32x16_bf16(af[mr], bf[nr], acc[mr][nr], 0, 0, 0);
    }
    cur ^= 1;
  }

  // ================= epilogue =================
  __syncthreads();                            // all waves done with LDS buffers
  const bool inst = cb < 40;
  const int cbl = inst ? cb : cb - 40;
  int* rl_s = (int*)(smem + 49152);
  if (inst && tid < 128) {
    int scol = cbl * 128 + tid;
    rl_s[tid] = (scol < NPID) ? rlab[scol] : PADMARK;
  }

  char* myreg = smem + w * 8704;              // 32 rows x 272B, XOR-swizzled cols
  const int rowq = l & 31;
  const int colh = l >> 5;

#pragma unroll
  for (int p = 0; p < 4; ++p) {
    // scatter acc[p] -> own LDS region (conflict-free: 32 lanes hit 32 banks)
#pragma unroll
    for (int nr = 0; nr < 2; ++nr)
#pragma unroll
      for (int reg = 0; reg < 16; ++reg) {
        int rl_ = (reg & 3) + ((reg >> 2) << 3) + ((l >> 5) << 2);
        int cl_ = nr * 32 + (l & 31);
        *(float*)(myreg + rl_ * 272 + ((cl_ ^ ((rl_ & 15) << 2)) << 2)) = acc[p][nr][reg];
      }
    __syncthreads();
    // gather: lane owns row rowq, cols colh*32..+31 (swizzled b128 reads)
    f32x4 v[8];
#pragma unroll
    for (int j = 0; j < 8; ++j)
      v[j] = *(const f32x4*)(myreg + rowq * 272 + ((((colh << 3) + j) ^ (rowq & 15)) << 4));

    const int growv = rb * 256 + wr * 128 + p * 32 + rowq;
    float m = NEGF;
    if (inst) {
      const int gv = g[growv];
#pragma unroll
      for (int j = 0; j < 8; ++j)
#pragma unroll
        for (int e = 0; e < 4; ++e) {
          int c = wc * 64 + colh * 32 + 4 * j + e;       // block-local col
          int rl = rl_s[c];
          float x2 = v[j][e] * SCALE2;
          bool pos = (rl == gv);
          if (pos) {
            int idx = atomicAdd(&poscnt[growv], 1);
            if (idx < 16) posbuf[growv * 16 + idx] = x2;
          }
          float xe = (pos || rl == PADMARK) ? NEGF : x2;
          v[j][e] = xe;
          m = fmaxf(m, xe);
        }
    } else {
      const int lrv = lr[growv];
      const int sbase = cbl * 128 + wc * 64 + colh * 32;
#pragma unroll
      for (int j = 0; j < 8; ++j)
#pragma unroll
        for (int e = 0; e < 4; ++e) {
          int scol = sbase + 4 * j + e;
          float x2 = v[j][e] * SCALE2;
          if (scol == lrv) target[growv] = x2;
          float xe = (scol < NPID) ? x2 : NEGF;
          v[j][e] = xe;
          m = fmaxf(m, xe);
        }
    }
    float ss = 0.f;
#pragma unroll
    for (int j = 0; j < 8; ++j)
#pragma unroll
      for (int e = 0; e < 4; ++e) ss += exp2f(v[j][e] - m);
    if (m <= -1e29f) ss = 0.f;                 // all-excluded lane
    float mo = __shfl_xor(m, 32, 64);
    float so = __shfl_xor(ss, 32, 64);
    float M = fmaxf(m, mo);
    float S = ss * exp2f(m - M) + so * exp2f(mo - M);
    if (colh == 0)
      partials[(size_t)growv * 160 + (inst ? 0 : 80) + cbl * 2 + wc] = make_float2(M, S);
    if (p < 3) __syncthreads();
  }
}

__global__ __launch_bounds__(256) void combine(const float2* __restrict__ partials,
                                               const float* __restrict__ posbuf,
                                               const int* __restrict__ poscnt,
                                               const float* __restrict__ target,
                                               const float* __restrict__ w2f,
                                               float* __restrict__ Lrow,
                                               float* __restrict__ Crow) {
  int row = blockIdx.x * 256 + threadIdx.x;
  if (row >= BT) return;
  const float2* p = partials + (size_t)row * 160;
  float M = NEGF, S = 0.f;
  for (int i = 0; i < 80; ++i) {
    float2 q = p[i];
    float M2 = fmaxf(M, q.x);
    S = S * exp2f(M - M2) + q.y * exp2f(q.x - M2);
    M = M2;
  }
  float lse2n = M + __log2f(S);                // base-2 lse of negatives
  int cnt = poscnt[row];
  int cc = cnt < 16 ? cnt : 16;
  float sum = 0.f;
  for (int j = 0; j < cc; ++j) {
    float d = LN2 * (lse2n - posbuf[row * 16 + j]);
    sum += (d > 60.f) ? d : log1pf(__expf(d));
  }
  float w2 = w2f[row];
  Lrow[row] = w2 * (sum / fmaxf((float)cnt, 1.0f));
  float M2 = NEGF, S2 = 0.f;
  for (int i = 80; i < 160; ++i) {
    float2 q = p[i];
    float Mx = fmaxf(M2, q.x);
    S2 = S2 * exp2f(M2 - Mx) + q.y * exp2f(q.x - Mx);
    M2 = Mx;
  }
  float ce = LN2 * (M2 + __log2f(S2) - target[row]);
  Crow[row] = w2 * ce;
}

__global__ __launch_bounds__(256) void finalize(const float* __restrict__ fc,
                                                const float* __restrict__ v1f,
                                                const float* __restrict__ w2f,
                                                const float* __restrict__ Lrow,
                                                const float* __restrict__ Crow,
                                                float* __restrict__ out) {
  int t = threadIdx.x;
  float s0 = 0, s1 = 0, s2 = 0, s3 = 0, s4 = 0;
  for (int r = t; r < BT; r += 256) {
    s0 += fc[r]; s1 += v1f[r]; s2 += w2f[r]; s3 += Lrow[r]; s4 += Crow[r];
  }
#pragma unroll
  for (int d = 1; d < 64; d <<= 1) {
    s0 += __shfl_xor(s0, d, 64);
    s1 += __shfl_xor(s1, d, 64);
    s2 += __shfl_xor(s2, d, 64);
    s3 += __shfl_xor(s3, d, 64);
    s4 += __shfl_xor(s4, d, 64);
  }
  __shared__ float red[4][5];
  int lane = t & 63, wv = t >> 6;
  if (lane == 0) { red[wv][0] = s0; red[wv][1] = s1; red[wv][2] = s2; red[wv][3] = s3; red[wv][4] = s4; }
  __syncthreads();
  if (t == 0) {
    float a0 = 0, a1 = 0, a2 = 0, a3 = 0, a4 = 0;
    for (int i = 0; i < 4; ++i) { a0 += red[i][0]; a1 += red[i][1]; a2 += red[i][2]; a3 += red[i][3]; a4 += red[i][4]; }
    float n1 = fmaxf(a1, 1.0f);
    float n2 = fmaxf(a2, 1.0f);
    out[0] = a0 / (n1 * (float)FDIM) + a4 / n2 + a3 / n2;
  }
}

extern "C" void kernel_launch(void* const* d_in, const int* in_sizes, int n_in,
                              void* d_out, int out_size, void* d_ws, size_t ws_size,
                              hipStream_t stream) {
  const float* inputs = (const float*)d_in[0];
  const int*   roi    = (const int*)d_in[1];
  const float* lut    = (const float*)d_in[2];
  const float* reid   = (const float*)d_in[3];
  const int*   rlab   = (const int*)d_in[4];
  float* out = (float*)d_out;

  char* w = (char*)d_ws;
  unsigned short* Ap = (unsigned short*)(w);                 // 6,291,456 B
  unsigned short* Bp = (unsigned short*)(w + 6291456);       // 15,728,640 B
  float2* partials   = (float2*)(w + 22020096);              // 5,242,880 B
  float*  posbuf     = (float*)(w + 27262976);               // 262,144 B
  int*    poscnt     = (int*)(w + 27525120);                 // 16,384 B
  float*  target     = (float*)(w + 27541504);
  int*    g          = (int*)(w + 27557888);
  int*    lr         = (int*)(w + 27574272);
  float*  w2f        = (float*)(w + 27590656);
  float*  v1f        = (float*)(w + 27607040);
  float*  fc         = (float*)(w + 27623424);
  float*  Lrow       = (float*)(w + 27639808);
  float*  Crow       = (float*)(w + 27656192);               // ends 27,672,576

  hipMemsetAsync(poscnt, 0, BT * sizeof(int), stream);
  convert_A<<<(BT * 96 + 255) / 256, 256, 0, stream>>>(inputs, Ap);
  convert_B<<<(BPROWS * 96 + 255) / 256, 256, 0, stream>>>(lut, reid, Bp);
  meta_fc<<<(BT * 64) / 256, 256, 0, stream>>>(inputs, roi, lut, rlab, g, lr, w2f, v1f, fc);
  gemm_main<<<1280, 256, 49664, stream>>>(Ap, Bp, rlab, g, lr, partials, posbuf, poscnt, target);
  combine<<<BT / 256, 256, 0, stream>>>(partials, posbuf, poscnt, target, w2f, Lrow, Crow);
  finalize<<<1, 256, 0, stream>>>(fc, v1f, w2f, Lrow, Crow, out);
}

// Round 3
// 130.309 us; speedup vs baseline: 1.7620x; 1.5200x over previous
//
#include <hip/hip_runtime.h>

// OIM unsupervised loss, MI355X/gfx950 — round 3.
// hi/lo-compensated bf16 GEMM (augmented K=768), mfma_f32_16x16x32_bf16,
// m97 structure: 128x128 tile, 4 waves @64x64, BK=64, single-buffer 32KB LDS,
// global_load_lds w=16, fragment-linear operands. Max-free exp2-sum epilogue
// (bounded logits), f32 chunk-major partials, XCD-bijective rb-fast swizzle.

#define BT 4096
#define NPID 5000
#define FDIM 256
#define KAUG 768
#define NCHUNK 24        // KAUG / 32
#define BPROWS 10240
#define SIDE 5120
#define SCALE2 43.2808512266689f   // 30*log2(e)
#define LN2 0.6931471805599453f
#define PADMARK ((int)0x80000000)

typedef __attribute__((ext_vector_type(8))) short short8;
typedef __attribute__((ext_vector_type(4))) float f32x4;

__device__ __forceinline__ unsigned short f2bf_rne(float f) {
  unsigned int u = __float_as_uint(f);
  u += 0x7fffu + ((u >> 16) & 1u);
  return (unsigned short)(u >> 16);
}
__device__ __forceinline__ float bf2f(unsigned short h) {
  return __uint_as_float(((unsigned int)h) << 16);
}

// 16B-unit index of (row, oct) in 16x16x32 fragment-linear layout.
// frag-block = 16 rows x 32 k = 1KB; lane = (row&15) + 16*(k>>3).
__device__ __forceinline__ size_t frag_unit(int row, int oct) {
  int c  = oct >> 2;   // 32-wide k-chunk
  int ko = oct & 3;    // 8-wide oct within chunk
  return ((size_t)(row >> 4) * NCHUNK + c) * 64 + (row & 15) + (ko << 4);
}

__global__ __launch_bounds__(256) void convert_A(const float* __restrict__ x,
                                                 unsigned short* __restrict__ outp) {
  int idx = blockIdx.x * 256 + threadIdx.x;
  if (idx >= BT * 96) return;
  int row = idx / 96, oct = idx % 96;
  int seg = oct >> 5;          // 0,1: hi   2: lo
  int so  = oct & 31;
  const float4* s4 = (const float4*)(x + (size_t)row * FDIM + so * 8);
  float4 f0 = s4[0], f1 = s4[1];
  float fv[8] = {f0.x, f0.y, f0.z, f0.w, f1.x, f1.y, f1.z, f1.w};
  short8 ov;
#pragma unroll
  for (int j = 0; j < 8; ++j) {
    unsigned short hi = f2bf_rne(fv[j]);
    if (seg == 2) hi = f2bf_rne(fv[j] - bf2f(hi));
    ov[j] = (short)hi;
  }
  *(short8*)(outp + frag_unit(row, oct) * 8) = ov;
}

__global__ __launch_bounds__(256) void convert_B(const float* __restrict__ lut,
                                                 const float* __restrict__ reid,
                                                 unsigned short* __restrict__ outp) {
  int idx = blockIdx.x * 256 + threadIdx.x;
  if (idx >= BPROWS * 96) return;
  int row = idx / 96, oct = idx % 96;
  int seg = oct >> 5;          // 0: hi  1: lo  2: hi
  int so  = oct & 31;
  const float* src = nullptr;
  if (row < NPID) src = lut + (size_t)row * FDIM + so * 8;
  else if (row >= SIDE && row < SIDE + NPID) src = reid + (size_t)(row - SIDE) * FDIM + so * 8;
  short8 ov;
  if (src) {
    const float4* s4 = (const float4*)src;
    float4 f0 = s4[0], f1 = s4[1];
    float fv[8] = {f0.x, f0.y, f0.z, f0.w, f1.x, f1.y, f1.z, f1.w};
#pragma unroll
    for (int j = 0; j < 8; ++j) {
      unsigned short hi = f2bf_rne(fv[j]);
      if (seg == 1) hi = f2bf_rne(fv[j] - bf2f(hi));
      ov[j] = (short)hi;
    }
  } else {
#pragma unroll
    for (int j = 0; j < 8; ++j) ov[j] = 0;
  }
  *(short8*)(outp + frag_unit(row, oct) * 8) = ov;
}

__global__ __launch_bounds__(256) void meta_fc(const float* __restrict__ inputs,
                                               const int* __restrict__ roi,
                                               const float* __restrict__ lut,
                                               const int* __restrict__ rlab,
                                               int* __restrict__ g, int* __restrict__ lr,
                                               float* __restrict__ w2f, float* __restrict__ v1f,
                                               float* __restrict__ fc) {
  int gt = blockIdx.x * 256 + threadIdx.x;
  int row = gt >> 6, lane = gt & 63;
  if (row >= BT) return;
  int t = roi[row] - 1;
  bool valid = t >= 0;
  int label = t > 0 ? t : 0;
  int gg = rlab[label];
  const float4* xv = (const float4*)(inputs + (size_t)row * FDIM);
  const float4* lv = (const float4*)(lut + (size_t)label * FDIM);
  float4 a = xv[lane], b = lv[lane];
  float dx = b.x - a.x, dy = b.y - a.y, dz = b.z - a.z, dw = b.w - a.w;
  float s = dx * dx + dy * dy + dz * dz + dw * dw;
#pragma unroll
  for (int d = 1; d < 64; d <<= 1) s += __shfl_xor(s, d, 64);
  if (lane == 0) {
    g[row]   = gg;
    lr[row]  = gg > 0 ? gg : 0;
    w2f[row] = (valid && gg >= 0) ? 1.0f : 0.0f;
    v1f[row] = valid ? 1.0f : 0.0f;
    fc[row]  = valid ? s : 0.0f;
  }
}

__global__ __launch_bounds__(256, 3) void gemm_main(const unsigned short* __restrict__ Ap,
                                                    const unsigned short* __restrict__ Bp,
                                                    const int* __restrict__ rlab,
                                                    const int* __restrict__ g,
                                                    const int* __restrict__ lr,
                                                    float* __restrict__ partials,
                                                    float* __restrict__ posbuf,
                                                    int* __restrict__ poscnt,
                                                    float* __restrict__ target) {
  __shared__ unsigned short lds[16384] __attribute__((aligned(16)));  // 32 KB
  // XCD-bijective, rb-fast swizzle: 2560 = 8 xcd * (80 cb * 4 rbl).
  // Each XCD keeps 4 A-panels L2-hot and streams each B-panel once.
  const int bid = blockIdx.x;
  const int xcd = bid & 7;
  const int i   = bid >> 3;
  const int cb  = i >> 2;              // 0..79 (0..39 inst, 40..79 reid)
  const int rb  = xcd * 4 + (i & 3);   // 0..31
  const int tid = threadIdx.x;
  const int l = tid & 63;
  const int w = tid >> 6;
  const int wr = w >> 1, wc = w & 1;

  f32x4 acc[4][4];
#pragma unroll
  for (int mi = 0; mi < 4; ++mi)
#pragma unroll
    for (int ni = 0; ni < 4; ++ni) acc[mi][ni] = (f32x4){0.f, 0.f, 0.f, 0.f};

  for (int s = 0; s < 12; ++s) {           // K-steps of 64 (2 mfma chunks)
    const int c0 = s * 2;
    __syncthreads();
#pragma unroll
    for (int q = 0; q < 8; ++q) {          // 32 frag-blocks of 1KB, 8 per wave
      const int f = w * 8 + q;
      const bool isA = f < 16;
      const int fl = isA ? f : f - 16;
      const int cc = fl >> 3;
      const int grp = fl & 7;
      const int gidx = isA ? (rb * 8 + grp) : (cb * 8 + grp);
      const unsigned short* src = (isA ? Ap : Bp)
          + (((size_t)gidx * NCHUNK + (c0 + cc)) << 6) * 8 + l * 8;
      unsigned short* dst = &lds[f * 512];
      __builtin_amdgcn_global_load_lds((const __attribute__((address_space(1))) unsigned int*)src,
                                       (__attribute__((address_space(3))) unsigned int*)dst,
                                       16, 0, 0);
    }
    __syncthreads();
#pragma unroll
    for (int cc = 0; cc < 2; ++cc) {
      short8 af[4], bfr[4];
#pragma unroll
      for (int mr = 0; mr < 4; ++mr)
        af[mr] = *(const short8*)&lds[(cc * 8 + (wr * 4 + mr)) * 512 + l * 8];
#pragma unroll
      for (int nr = 0; nr < 4; ++nr)
        bfr[nr] = *(const short8*)&lds[8192 + (cc * 8 + (wc * 4 + nr)) * 512 + l * 8];
#pragma unroll
      for (int mr = 0; mr < 4; ++mr)
#pragma unroll
        for (int nr = 0; nr < 4; ++nr)
          acc[mr][nr] = __builtin_amdgcn_mfma_f32_16x16x32_bf16(af[mr], bfr[nr], acc[mr][nr], 0, 0, 0);
    }
  }

  // ---- epilogue: max-free exp2 sums (logits bounded by |43.3| in base-2) ----
  const bool inst = cb < 40;
  const int cbl = inst ? cb : cb - 40;
  int scol[4], rl4[4];
#pragma unroll
  for (int nr = 0; nr < 4; ++nr) {
    scol[nr] = cbl * 128 + wc * 64 + nr * 16 + (l & 15);     // side-local col
    rl4[nr] = (inst && scol[nr] < NPID) ? rlab[scol[nr]] : PADMARK;
  }
  const int rowbase = rb * 128 + wr * 64 + ((l >> 4) << 2);
  const int chunk = (inst ? 0 : 80) + cbl * 2 + wc;

#pragma unroll
  for (int mr = 0; mr < 4; ++mr) {
#pragma unroll
    for (int reg = 0; reg < 4; ++reg) {
      const int row = rowbase + mr * 16 + reg;
      float s = 0.f;
      if (inst) {
        const int gv = g[row];
#pragma unroll
        for (int nr = 0; nr < 4; ++nr) {
          float x2 = acc[mr][nr][reg] * SCALE2;
          bool pos = (rl4[nr] == gv);
          if (pos) {
            int idx = atomicAdd(&poscnt[row], 1);
            if (idx < 16) posbuf[row * 16 + idx] = x2;
          }
          if (!pos && rl4[nr] != PADMARK) s += exp2f(x2);
        }
      } else {
        const int lrv = lr[row];
#pragma unroll
        for (int nr = 0; nr < 4; ++nr) {
          float x2 = acc[mr][nr][reg] * SCALE2;
          if (scol[nr] == lrv) target[row] = x2;
          if (scol[nr] < NPID) s += exp2f(x2);
        }
      }
#pragma unroll
      for (int d = 1; d < 16; d <<= 1) s += __shfl_xor(s, d, 64);
      if ((l & 15) == 0) partials[(size_t)chunk * BT + row] = s;
    }
  }
}

__global__ __launch_bounds__(256) void combine(const float* __restrict__ partials,
                                               const float* __restrict__ posbuf,
                                               const int* __restrict__ poscnt,
                                               const float* __restrict__ target,
                                               const float* __restrict__ w2f,
                                               float* __restrict__ Lrow,
                                               float* __restrict__ Crow) {
  int row = blockIdx.x * 256 + threadIdx.x;
  if (row >= BT) return;
  float S = 0.f;
  for (int i = 0; i < 80; ++i) S += partials[(size_t)i * BT + row];
  float lse2n = __log2f(S);                 // base-2 lse of negatives
  int cnt = poscnt[row];
  int cc = cnt < 16 ? cnt : 16;
  float sum = 0.f;
  for (int j = 0; j < cc; ++j) {
    float d = LN2 * (lse2n - posbuf[row * 16 + j]);
    sum += (d > 60.f) ? d : log1pf(__expf(d));
  }
  float w2 = w2f[row];
  Lrow[row] = w2 * (sum / fmaxf((float)cnt, 1.0f));
  float S2 = 0.f;
  for (int i = 80; i < 160; ++i) S2 += partials[(size_t)i * BT + row];
  Crow[row] = w2 * LN2 * (__log2f(S2) - target[row]);
}

__global__ __launch_bounds__(256) void finalize(const float* __restrict__ fc,
                                                const float* __restrict__ v1f,
                                                const float* __restrict__ w2f,
                                                const float* __restrict__ Lrow,
                                                const float* __restrict__ Crow,
                                                float* __restrict__ out) {
  int t = threadIdx.x;
  float s0 = 0, s1 = 0, s2 = 0, s3 = 0, s4 = 0;
  for (int r = t; r < BT; r += 256) {
    s0 += fc[r]; s1 += v1f[r]; s2 += w2f[r]; s3 += Lrow[r]; s4 += Crow[r];
  }
#pragma unroll
  for (int d = 1; d < 64; d <<= 1) {
    s0 += __shfl_xor(s0, d, 64);
    s1 += __shfl_xor(s1, d, 64);
    s2 += __shfl_xor(s2, d, 64);
    s3 += __shfl_xor(s3, d, 64);
    s4 += __shfl_xor(s4, d, 64);
  }
  __shared__ float red[4][5];
  int lane = t & 63, wv = t >> 6;
  if (lane == 0) { red[wv][0] = s0; red[wv][1] = s1; red[wv][2] = s2; red[wv][3] = s3; red[wv][4] = s4; }
  __syncthreads();
  if (t == 0) {
    float a0 = 0, a1 = 0, a2 = 0, a3 = 0, a4 = 0;
    for (int i = 0; i < 4; ++i) { a0 += red[i][0]; a1 += red[i][1]; a2 += red[i][2]; a3 += red[i][3]; a4 += red[i][4]; }
    float n1 = fmaxf(a1, 1.0f);
    float n2 = fmaxf(a2, 1.0f);
    out[0] = a0 / (n1 * (float)FDIM) + a4 / n2 + a3 / n2;
  }
}

extern "C" void kernel_launch(void* const* d_in, const int* in_sizes, int n_in,
                              void* d_out, int out_size, void* d_ws, size_t ws_size,
                              hipStream_t stream) {
  const float* inputs = (const float*)d_in[0];
  const int*   roi    = (const int*)d_in[1];
  const float* lut    = (const float*)d_in[2];
  const float* reid   = (const float*)d_in[3];
  const int*   rlab   = (const int*)d_in[4];
  float* out = (float*)d_out;

  char* w = (char*)d_ws;
  unsigned short* Ap = (unsigned short*)(w);                 // 6,291,456 B
  unsigned short* Bp = (unsigned short*)(w + 6291456);       // 15,728,640 B -> 22,020,096
  float* partials    = (float*)(w + 22020096);               // 2,621,440 B  -> 24,641,536
  float* posbuf      = (float*)(w + 24641536);               // 262,144 B    -> 24,903,680
  int*   poscnt      = (int*)(w + 24903680);                 // 16,384 B     -> 24,920,064
  float* target      = (float*)(w + 24920064);               // 16,384 B     -> 24,936,448
  int*   g           = (int*)(w + 24936448);                 // 16,384 B     -> 24,952,832
  int*   lr          = (int*)(w + 24952832);                 // 16,384 B     -> 24,969,216
  float* w2f         = (float*)(w + 24969216);               // 16,384 B     -> 24,985,600
  float* v1f         = (float*)(w + 24985600);               // 16,384 B     -> 25,001,984
  float* fc          = (float*)(w + 25001984);               // 16,384 B     -> 25,018,368
  float* Lrow        = (float*)(w + 25018368);               // 16,384 B     -> 25,034,752
  float* Crow        = (float*)(w + 25034752);               // 16,384 B     -> 25,051,136

  hipMemsetAsync(poscnt, 0, BT * sizeof(int), stream);
  convert_A<<<(BT * 96 + 255) / 256, 256, 0, stream>>>(inputs, Ap);
  convert_B<<<(BPROWS * 96 + 255) / 256, 256, 0, stream>>>(lut, reid, Bp);
  meta_fc<<<(BT * 64) / 256, 256, 0, stream>>>(inputs, roi, lut, rlab, g, lr, w2f, v1f, fc);
  gemm_main<<<2560, 256, 0, stream>>>(Ap, Bp, rlab, g, lr, partials, posbuf, poscnt, target);
  combine<<<BT / 256, 256, 0, stream>>>(partials, posbuf, poscnt, target, w2f, Lrow, Crow);
  finalize<<<1, 256, 0, stream>>>(fc, v1f, w2f, Lrow, Crow, out);
}